// Round 15
// baseline (1010.294 us; speedup 1.0000x reference)
//
#include <hip/hip_runtime.h>
#include <math.h>

#define N_NODES 20000
#define MPAD 20096            // 157 * 128
#define E_EDGES 320000
#define ET (E_EDGES + N_NODES)   // edges incl. self-loops
#define C_HID 640
#define C_IN 128
#define NEG_SLOPE 0.2f

// GEMM tiling: BM=128, BN=64, BK=64; grid = NXB x 10 flattened with XCD swizzle
#define NXB 157               // MPAD/128
#define NYB 10                // C_HID/64
#define NXB_FULL 152          // (NXB/8)*8
#define IDS_MAIN 1520         // NXB_FULL * NYB

typedef __attribute__((ext_vector_type(8))) short bf16x8;   // 8 bf16 in 4 VGPRs
typedef __attribute__((ext_vector_type(4))) float f32x4;

__device__ __forceinline__ float leaky(float x) { return x > 0.f ? x : NEG_SLOPE * x; }

__device__ __forceinline__ unsigned short f2bf(float f) {
    unsigned u = __float_as_uint(f);
    unsigned r = (u + 0x7fffu + ((u >> 16) & 1u)) >> 16;
    return (unsigned short)r;
}
__device__ __forceinline__ float bf2f(unsigned short h) {
    return __uint_as_float(((unsigned)h) << 16);
}

__device__ __forceinline__ void gld16(const void* g, void* l) {
    __builtin_amdgcn_global_load_lds((const __attribute__((address_space(1))) unsigned int*)g,
                                     (__attribute__((address_space(3))) unsigned int*)l,
                                     16, 0, 0);
}

// XCD-aware swizzle: blocks sharing an A-stripe (same bx) get ids 8 apart -> same XCD (id%8)
__device__ __forceinline__ void decode_xy(int id, int& bx, int& by) {
    if (id < IDS_MAIN) {
        int g = id / 80;               // 80 = 8 bx * 10 by per group
        bx = g * 8 + (id & 7);
        by = (id % 80) >> 3;
    } else {
        int v = id - IDS_MAIN;         // 5 bx * 10 by tail
        bx = NXB_FULL + v % 5;
        by = v / 5;
    }
}

// ---------------- CSR build (by dst) ----------------
__global__ void k_zero(int* p, int n) {
    int i = blockIdx.x * blockDim.x + threadIdx.x;
    if (i < n) p[i] = 0;
}

__global__ void k_count(const int* __restrict__ ei, int* __restrict__ counts) {
    int j = blockIdx.x * blockDim.x + threadIdx.x;
    if (j >= ET) return;
    int d = (j < E_EDGES) ? ei[E_EDGES + j] : (j - E_EDGES);
    atomicAdd(&counts[d], 1);
}

// single-block scan; also overwrites counts[] with the exclusive prefix (cursor for k_fill)
__global__ __launch_bounds__(1024) void k_scan(int* __restrict__ counts,
                                               int* __restrict__ rowptr) {
    __shared__ int part[1024];
    int t = threadIdx.x;
    int base = t * 20;
    int incl[20];
    int s = 0;
#pragma unroll
    for (int k = 0; k < 20; k++) {
        int i = base + k;
        int v = (i < N_NODES) ? counts[i] : 0;
        s += v;
        incl[k] = s;
    }
    part[t] = s;
    __syncthreads();
    for (int off = 1; off < 1024; off <<= 1) {
        int x = (t >= off) ? part[t - off] : 0;
        __syncthreads();
        part[t] += x;
        __syncthreads();
    }
    int prefix = (t == 0) ? 0 : part[t - 1];
    if (t == 0) rowptr[0] = 0;
#pragma unroll
    for (int k = 0; k < 20; k++) {
        int i = base + k;
        if (i < N_NODES) {
            rowptr[i + 1] = prefix + incl[k];
            counts[i] = (k == 0) ? prefix : prefix + incl[k - 1];   // exclusive = row start
        }
    }
}

// fills CSR col; also zeroes the 16-entry pad past col[ET] (safe masked-group overruns)
__global__ void k_fill(const int* __restrict__ ei, int* __restrict__ cursor, int* __restrict__ col) {
    int j = blockIdx.x * blockDim.x + threadIdx.x;
    if (j >= ET) {
        if (j < ET + 16) col[j] = 0;
        return;
    }
    int s, d;
    if (j < E_EDGES) { s = ei[j]; d = ei[E_EDGES + j]; }
    else { s = d = j - E_EDGES; }
    int pos = atomicAdd(&cursor[d], 1);
    col[pos] = s;
}

// ---------------- W transpose+split, LDS-tiled; also zeroes as_/ad_ (fused zerof) ----------------
__global__ __launch_bounds__(256) void k_splitWT(const float* __restrict__ W,
                                                 unsigned short* __restrict__ Wth,
                                                 unsigned short* __restrict__ Wtl, int K,
                                                 float* __restrict__ zbuf, int zn) {
    if (zbuf) {   // fused as_/ad_ zeroing
        int tid = ((blockIdx.y * gridDim.x + blockIdx.x) * 256 + threadIdx.x) * 2;
        if (tid < zn) zbuf[tid] = 0.f;
        if (tid + 1 < zn) zbuf[tid + 1] = 0.f;
    }
    __shared__ float tile[64][65];
    int t = threadIdx.x;
    int ki = blockIdx.x * 64, ni = blockIdx.y * 64;
    int tr = t >> 2;                 // 0..63
    int tc = (t & 3) * 16;           // 0,16,32,48
#pragma unroll
    for (int q = 0; q < 4; ++q) {
        float4 v = *(const float4*)&W[(size_t)(ki + tr) * C_HID + ni + tc + q * 4];
        tile[tr][tc + q * 4 + 0] = v.x;
        tile[tr][tc + q * 4 + 1] = v.y;
        tile[tr][tc + q * 4 + 2] = v.z;
        tile[tr][tc + q * 4 + 3] = v.w;
    }
    __syncthreads();
    unsigned short hh[16], ll[16];
#pragma unroll
    for (int j = 0; j < 16; ++j) {
        float w = tile[tc + j][tr];
        unsigned short h = f2bf(w);
        hh[j] = h;
        ll[j] = f2bf(w - bf2f(h));
    }
    size_t o = (size_t)(ni + tr) * K + ki + tc;
#pragma unroll
    for (int q = 0; q < 4; ++q) {
        *(ushort4*)&Wth[o + q * 4] = make_ushort4(hh[q*4], hh[q*4+1], hh[q*4+2], hh[q*4+3]);
        *(ushort4*)&Wtl[o + q * 4] = make_ushort4(ll[q*4], ll[q*4+1], ll[q*4+2], ll[q*4+3]);
    }
}

// zero pad rows of xa pair [MPAD,128] and pair [MPAD,640]
__global__ void k_padzero(unsigned short* __restrict__ xah, unsigned short* __restrict__ xal,
                          unsigned short* __restrict__ ph, unsigned short* __restrict__ pl) {
    int idx = blockIdx.x * blockDim.x + threadIdx.x;
    const int nx = (MPAD - N_NODES) * C_IN;
    const int np = (MPAD - N_NODES) * C_HID;
    if (idx < nx) {
        xah[N_NODES * C_IN + idx] = 0;
        xal[N_NODES * C_IN + idx] = 0;
    }
    if (idx < np) {
        ph[N_NODES * C_HID + idx] = 0;
        pl[N_NODES * C_HID + idx] = 0;
    }
}

// ws = W1 @ a_src (len 128), wd = W1 @ a_dst — 128 waves = 32 blocks
__global__ void k_wa(const float* __restrict__ W, const float* __restrict__ a_s,
                     const float* __restrict__ a_d,
                     float* __restrict__ ws_, float* __restrict__ wd_) {
    int wave = (blockIdx.x * blockDim.x + threadIdx.x) >> 6;
    int lane = threadIdx.x & 63;
    if (wave >= C_IN) return;
    const float* row = W + (size_t)wave * C_HID;
    float s = 0.f, d = 0.f;
#pragma unroll
    for (int c = lane; c < C_HID; c += 64) {
        float w = row[c];
        s = fmaf(w, a_s[c], s);
        d = fmaf(w, a_d[c], d);
    }
    for (int o = 32; o; o >>= 1) { s += __shfl_xor(s, o); d += __shfl_xor(d, o); }
    if (lane == 0) { ws_[wave] = s; wd_[wave] = d; }
}

// as_[n] = x[n,:].ws, ad_[n] = x[n,:].wd — wave per node
__global__ __launch_bounds__(256) void k_logitx(const float* __restrict__ x,
                                                const float* __restrict__ ws_,
                                                const float* __restrict__ wd_,
                                                float* __restrict__ as_, float* __restrict__ ad_) {
    int wave = (blockIdx.x * blockDim.x + threadIdx.x) >> 6;
    int lane = threadIdx.x & 63;
    if (wave >= N_NODES) return;
    float2 xv = ((const float2*)(x + (size_t)wave * C_IN))[lane];
    float2 wsv = ((const float2*)ws_)[lane];
    float2 wdv = ((const float2*)wd_)[lane];
    float s = xv.x * wsv.x + xv.y * wsv.y;
    float d = xv.x * wdv.x + xv.y * wdv.y;
    for (int o = 32; o; o >>= 1) { s += __shfl_xor(s, o); d += __shfl_xor(d, o); }
    if (lane == 0) { as_[wave] = s; ad_[wave] = d; }
}

// ---------------- per-edge softmax weights (layers 2-4): wave per dst node ----------------
__global__ __launch_bounds__(256) void k_alpha(const float* __restrict__ as_,
                                               const float* __restrict__ ad_,
                                               const int* __restrict__ rowptr,
                                               const int* __restrict__ col,
                                               float* __restrict__ alpha) {
    int wave = (blockIdx.x * blockDim.x + threadIdx.x) >> 6;
    int lane = threadIdx.x & 63;
    if (wave >= N_NODES) return;
    int start = rowptr[wave], end = rowptr[wave + 1];
    float adi = ad_[wave];
    float m = -1e30f;
    for (int j = start + lane; j < end; j += 64)
        m = fmaxf(m, leaky(as_[col[j]] + adi));
    for (int o = 32; o; o >>= 1) m = fmaxf(m, __shfl_xor(m, o));
    float den = 0.f;
    for (int j = start + lane; j < end; j += 64)
        den += __expf(leaky(as_[col[j]] + adi) - m);
    for (int o = 32; o; o >>= 1) den += __shfl_xor(den, o);
    float inv = 1.f / den;
    for (int j = start + lane; j < end; j += 64)
        alpha[j] = __expf(leaky(as_[col[j]] + adi) - m) * inv;
}

// ---------------- split-bf16 MFMA GEMM (BM=128,BN=64,BK=64) + fused logits (layers 2-4) ----------------
__global__ __launch_bounds__(256) void k_mfma_gemm(
    const unsigned short* __restrict__ Ahi, const unsigned short* __restrict__ Alo,
    const unsigned short* __restrict__ Bth, const unsigned short* __restrict__ Btl,
    float* __restrict__ C, int K, int M,
    const float* __restrict__ asrc, const float* __restrict__ adst,
    float* __restrict__ as_, float* __restrict__ ad_) {
    __shared__ unsigned short lds[24576];
    const int t = threadIdx.x;
    const int lane = t & 63, wv = t >> 6;
    const int wm = wv >> 1, wn = wv & 1;
    const int quad = lane >> 4, cl = lane & 15;
    int bx, by;
    decode_xy(blockIdx.x, bx, by);
    const int rowBase = bx * 128;
    const int colBase = by * 64;
    const int sr = t >> 3;                 // staging row within 32-row pass
    const int scg = ((t & 7) ^ (sr & 7)) * 8;   // swizzled global chunk (ushort off)

    f32x4 acc[4][2];
#pragma unroll
    for (int i = 0; i < 4; i++)
#pragma unroll
        for (int j = 0; j < 2; j++)
            acc[i][j] = (f32x4){0.f, 0.f, 0.f, 0.f};

    for (int k0 = 0; k0 < K; k0 += 64) {
        __syncthreads();
#pragma unroll
        for (int p = 0; p < 4; ++p) {       // A pair: 128 rows
            int r = p * 32 + sr;
            size_t ga = (size_t)(rowBase + r) * K + k0 + scg;
            int lo = p * 2048 + t * 8;
            gld16(Ahi + ga, &lds[lo]);
            gld16(Alo + ga, &lds[8192 + lo]);
        }
#pragma unroll
        for (int p = 0; p < 2; ++p) {       // B pair: 64 rows
            int r = p * 32 + sr;
            size_t gb = (size_t)(colBase + r) * K + k0 + scg;
            int lo = p * 2048 + t * 8;
            gld16(Bth + gb, &lds[16384 + lo]);
            gld16(Btl + gb, &lds[20480 + lo]);
        }
        __syncthreads();

#pragma unroll
        for (int ks = 0; ks < 2; ++ks) {
            bf16x8 ah[4], al[4], bh[2], bl[2];
#pragma unroll
            for (int i = 0; i < 4; ++i) {
                int row = wm * 64 + i * 16 + cl;
                int am = row * 64 + (((ks * 4 + quad) ^ (row & 7)) * 8);
                ah[i] = *(const bf16x8*)&lds[am];
                al[i] = *(const bf16x8*)&lds[8192 + am];
            }
#pragma unroll
            for (int j = 0; j < 2; ++j) {
                int row = wn * 32 + j * 16 + cl;
                int bn = row * 64 + (((ks * 4 + quad) ^ (row & 7)) * 8);
                bh[j] = *(const bf16x8*)&lds[16384 + bn];
                bl[j] = *(const bf16x8*)&lds[20480 + bn];
            }
#pragma unroll
            for (int i = 0; i < 4; ++i)
#pragma unroll
                for (int j = 0; j < 2; ++j) {
                    acc[i][j] = __builtin_amdgcn_mfma_f32_16x16x32_bf16(ah[i], bh[j], acc[i][j], 0, 0, 0);
                    acc[i][j] = __builtin_amdgcn_mfma_f32_16x16x32_bf16(ah[i], bl[j], acc[i][j], 0, 0, 0);
                    acc[i][j] = __builtin_amdgcn_mfma_f32_16x16x32_bf16(al[i], bh[j], acc[i][j], 0, 0, 0);
                }
        }
    }

    // C stores; C/D layout: col = lane&15, row = quad*4 + reg
#pragma unroll
    for (int i = 0; i < 4; ++i)
#pragma unroll
        for (int j = 0; j < 2; ++j) {
            int colC = colBase + wn * 32 + j * 16 + cl;
#pragma unroll
            for (int rr = 0; rr < 4; ++rr) {
                int rowC = rowBase + wm * 64 + i * 16 + quad * 4 + rr;
                if (rowC < M) C[(size_t)rowC * C_HID + colC] = acc[i][j][rr];
            }
        }

    // fused logits epilogue
    float av[2], dv[2];
#pragma unroll
    for (int j = 0; j < 2; ++j) {
        int cn = colBase + wn * 32 + j * 16 + cl;
        av[j] = asrc[cn];
        dv[j] = adst[cn];
    }
#pragma unroll
    for (int i = 0; i < 4; ++i)
#pragma unroll
        for (int rr = 0; rr < 4; ++rr) {
            float s = 0.f, d = 0.f;
#pragma unroll
            for (int j = 0; j < 2; ++j) {
                float v = acc[i][j][rr];
                s = fmaf(v, av[j], s);
                d = fmaf(v, dv[j], d);
            }
#pragma unroll
            for (int o = 8; o >= 1; o >>= 1) {
                s += __shfl_xor(s, o);
                d += __shfl_xor(d, o);
            }
            int rowC = rowBase + wm * 64 + i * 16 + quad * 4 + rr;
            if (cl == 0 && rowC < M) {
                atomicAdd(&as_[rowC], s);
                atomicAdd(&ad_[rowC], d);
            }
        }
}

// ---------------- layer-1 GEMM (BK=64): pair output epilogue (bias+relu+split) ----------------
__global__ __launch_bounds__(256) void k_mfma_gemm_pair(
    const unsigned short* __restrict__ Ahi, const unsigned short* __restrict__ Alo,
    const unsigned short* __restrict__ Bth, const unsigned short* __restrict__ Btl,
    unsigned short* __restrict__ Oh, unsigned short* __restrict__ Ol,
    const float* __restrict__ bias, int K, int M) {
    __shared__ unsigned short lds[24576];
    const int t = threadIdx.x;
    const int lane = t & 63, wv = t >> 6;
    const int wm = wv >> 1, wn = wv & 1;
    const int quad = lane >> 4, cl = lane & 15;
    int bx, by;
    decode_xy(blockIdx.x, bx, by);
    const int rowBase = bx * 128;
    const int colBase = by * 64;
    const int sr = t >> 3;
    const int scg = ((t & 7) ^ (sr & 7)) * 8;

    f32x4 acc[4][2];
#pragma unroll
    for (int i = 0; i < 4; i++)
#pragma unroll
        for (int j = 0; j < 2; j++)
            acc[i][j] = (f32x4){0.f, 0.f, 0.f, 0.f};

    for (int k0 = 0; k0 < K; k0 += 64) {
        __syncthreads();
#pragma unroll
        for (int p = 0; p < 4; ++p) {
            int r = p * 32 + sr;
            size_t ga = (size_t)(rowBase + r) * K + k0 + scg;
            int lo = p * 2048 + t * 8;
            gld16(Ahi + ga, &lds[lo]);
            gld16(Alo + ga, &lds[8192 + lo]);
        }
#pragma unroll
        for (int p = 0; p < 2; ++p) {
            int r = p * 32 + sr;
            size_t gb = (size_t)(colBase + r) * K + k0 + scg;
            int lo = p * 2048 + t * 8;
            gld16(Bth + gb, &lds[16384 + lo]);
            gld16(Btl + gb, &lds[20480 + lo]);
        }
        __syncthreads();

#pragma unroll
        for (int ks = 0; ks < 2; ++ks) {
            bf16x8 ah[4], al[4], bh[2], bl[2];
#pragma unroll
            for (int i = 0; i < 4; ++i) {
                int row = wm * 64 + i * 16 + cl;
                int am = row * 64 + (((ks * 4 + quad) ^ (row & 7)) * 8);
                ah[i] = *(const bf16x8*)&lds[am];
                al[i] = *(const bf16x8*)&lds[8192 + am];
            }
#pragma unroll
            for (int j = 0; j < 2; ++j) {
                int row = wn * 32 + j * 16 + cl;
                int bn = row * 64 + (((ks * 4 + quad) ^ (row & 7)) * 8);
                bh[j] = *(const bf16x8*)&lds[16384 + bn];
                bl[j] = *(const bf16x8*)&lds[20480 + bn];
            }
#pragma unroll
            for (int i = 0; i < 4; ++i)
#pragma unroll
                for (int j = 0; j < 2; ++j) {
                    acc[i][j] = __builtin_amdgcn_mfma_f32_16x16x32_bf16(ah[i], bh[j], acc[i][j], 0, 0, 0);
                    acc[i][j] = __builtin_amdgcn_mfma_f32_16x16x32_bf16(ah[i], bl[j], acc[i][j], 0, 0, 0);
                    acc[i][j] = __builtin_amdgcn_mfma_f32_16x16x32_bf16(al[i], bh[j], acc[i][j], 0, 0, 0);
                }
        }
    }

#pragma unroll
    for (int j = 0; j < 2; ++j) {
        int colC = colBase + wn * 32 + j * 16 + cl;
        float bv = bias[colC];
#pragma unroll
        for (int i = 0; i < 4; ++i)
#pragma unroll
            for (int rr = 0; rr < 4; ++rr) {
                int rowC = rowBase + wm * 64 + i * 16 + quad * 4 + rr;
                if (rowC < M) {
                    float v = fmaxf(acc[i][j][rr] + bv, 0.f);   // ReLU (layer 1)
                    unsigned short h = f2bf(v);
                    Oh[(size_t)rowC * C_HID + colC] = h;
                    Ol[(size_t)rowC * C_HID + colC] = f2bf(v - bf2f(h));
                }
            }
    }
}

// ---------------- weighted gather (layers 2-4): wave = (2 nodes, 32-col chunk) ----------------
// 32-col slices: hot set 2.55 MB fits per-XCD 4MB L2 (capacity misses ~gone).
// Lanes 0-31 = node A, 32-63 = node B; col/alpha stay batched contiguous scalar loads;
// per-lane row address = cndmask of two scalars; each vector load = two 128B segments.
__global__ __launch_bounds__(256) void k_gather32(const float* __restrict__ hW,
                                                  const float* __restrict__ alpha,
                                                  const int* __restrict__ rowptr,
                                                  const int* __restrict__ col,
                                                  const float* __restrict__ bias,
                                                  unsigned short* __restrict__ outh,
                                                  unsigned short* __restrict__ outl) {
    int lane = threadIdx.x & 63;
    int half = lane >> 5;              // 0: node A, 1: node B
    int cl = lane & 31;
    int pairId = __builtin_amdgcn_readfirstlane(blockIdx.x * 4 + (threadIdx.x >> 6));
    int c = blockIdx.y;                // 0..19 slice
    int nodeA = pairId * 2;
    int sA = rowptr[nodeA], eA = rowptr[nodeA + 1], eB = rowptr[nodeA + 2];
    int degA = eA - sA, degB = eB - eA;
    int G = (max(degA, degB) + 15) >> 4;
    const float* base = hW + c * 32 + cl;
    float ax = 0.f;

    for (int g = 0; g < G; ++g) {
        int jA = sA + g * 16, jB = eA + g * 16;
        int cvA[16], cvB[16];
        float avA[16], avB[16];
#pragma unroll
        for (int q = 0; q < 16; ++q) {        // contiguous scalar batches (col pad zeroed)
            cvA[q] = col[jA + q];
            cvB[q] = col[jB + q];
            avA[q] = (jA + q < eA) ? alpha[jA + q] : 0.f;
            avB[q] = (jB + q < eB) ? alpha[jB + q] : 0.f;
        }
        float r[16], a[16];
#pragma unroll
        for (int q = 0; q < 16; ++q) {
            int s = half ? cvB[q] : cvA[q];    // v_cndmask of two SGPRs
            a[q] = half ? avB[q] : avA[q];
            r[q] = base[(size_t)s * C_HID];    // two 128B segments per load
        }
#pragma unroll
        for (int q = 0; q < 16; ++q) ax = fmaf(a[q], r[q], ax);
    }

    int node = nodeA + half;
    float v0 = fmaxf(ax + bias[c * 32 + cl], 0.f);   // layers 2-4 ReLU
    unsigned short h0 = f2bf(v0);
    size_t o = (size_t)node * C_HID + c * 32 + cl;
    outh[o] = h0;
    outl[o] = f2bf(v0 - bf2f(h0));
}

// ---------------- layer-1 gather: fused softmax + gather raw x (128 cols, single pass) ----------------
__global__ __launch_bounds__(256) void k_gather_x(const float* __restrict__ x,
                                                  const float* __restrict__ as_,
                                                  const float* __restrict__ ad_,
                                                  const int* __restrict__ rowptr,
                                                  const int* __restrict__ col,
                                                  unsigned short* __restrict__ outh,
                                                  unsigned short* __restrict__ outl) {
    int wv = threadIdx.x >> 6, lane = threadIdx.x & 63;
    int node = blockIdx.x * 4 + wv;
    if (node >= N_NODES) return;
    int start = rowptr[node], end = rowptr[node + 1];
    int deg = end - start;
    const float* base = x + lane * 2;
    float ax = 0.f, ay = 0.f;
    float adi = ad_[node];

    if (deg <= 64) {
        int col_v = col[start + min(lane, deg - 1)];
        float asv = as_[col_v];
        float logit = (lane < deg) ? leaky(asv + adi) : -1e30f;
        float m = logit;
#pragma unroll
        for (int o = 32; o; o >>= 1) m = fmaxf(m, __shfl_xor(m, o));
        float ex = __expf(logit - m);
        float den = ex;
#pragma unroll
        for (int o = 32; o; o >>= 1) den += __shfl_xor(den, o);
        float alpha_v = ex / den;

        for (int e0 = 0; e0 < deg; e0 += 8) {
            float2 r[8];
            float a[8];
#pragma unroll
            for (int q = 0; q < 8; ++q) {
                int e = e0 + q;
                int ec = min(e, deg - 1);
                int s = __shfl(col_v, ec);
                float ar = __shfl(alpha_v, ec);
                a[q] = (e < deg) ? ar : 0.f;
                r[q] = *(const float2*)(base + (size_t)s * C_IN);
            }
#pragma unroll
            for (int q = 0; q < 8; ++q) {
                ax = fmaf(a[q], r[q].x, ax);
                ay = fmaf(a[q], r[q].y, ay);
            }
        }
    } else {
        float m = -1e30f;
        for (int j = start + lane; j < end; j += 64)
            m = fmaxf(m, leaky(as_[col[j]] + adi));
        for (int o = 32; o; o >>= 1) m = fmaxf(m, __shfl_xor(m, o));
        float den = 0.f;
        for (int j = start + lane; j < end; j += 64)
            den += __expf(leaky(as_[col[j]] + adi) - m);
        for (int o = 32; o; o >>= 1) den += __shfl_xor(den, o);
        float inv = 1.f / den;
        for (int j = start; j < end; ++j) {
            int s = col[j];
            float a = __expf(leaky(as_[s] + adi) - m) * inv;
            float2 r = *(const float2*)(base + (size_t)s * C_IN);
            ax = fmaf(a, r.x, ax);
            ay = fmaf(a, r.y, ay);
        }
    }

    unsigned short h0 = f2bf(ax), h1 = f2bf(ay);
    size_t o = (size_t)node * C_IN + lane * 2;
    *(ushort2*)&outh[o] = make_ushort2(h0, h1);
    *(ushort2*)&outl[o] = make_ushort2(f2bf(ax - bf2f(h0)), f2bf(ay - bf2f(h1)));
}

// ---------------- layer 5 (Co=2): hW5 + fused logits ----------------
__global__ __launch_bounds__(256) void k_gemm2(const unsigned short* __restrict__ hh,
                                               const unsigned short* __restrict__ hl,
                                               const float* __restrict__ W,
                                               const float* __restrict__ asrc,
                                               const float* __restrict__ adst,
                                               float* __restrict__ hW5,
                                               float* __restrict__ as_,
                                               float* __restrict__ ad_) {
    int wave = (blockIdx.x * blockDim.x + threadIdx.x) >> 6;
    int lane = threadIdx.x & 63;
    if (wave >= N_NODES) return;
    const ushort2* rh = (const ushort2*)(hh + (size_t)wave * C_HID);
    const ushort2* rl = (const ushort2*)(hl + (size_t)wave * C_HID);
    float a0 = 0.f, a1 = 0.f;
#pragma unroll
    for (int k2 = lane; k2 < C_HID / 2; k2 += 64) {
        ushort2 h2 = rh[k2];
        ushort2 l2 = rl[k2];
        float v0 = bf2f(h2.x) + bf2f(l2.x);
        float v1 = bf2f(h2.y) + bf2f(l2.y);
        int k = k2 * 2;
        a0 = fmaf(v0, W[k * 2 + 0], a0);
        a1 = fmaf(v0, W[k * 2 + 1], a1);
        a0 = fmaf(v1, W[k * 2 + 2], a0);
        a1 = fmaf(v1, W[k * 2 + 3], a1);
    }
    for (int o = 32; o; o >>= 1) { a0 += __shfl_xor(a0, o); a1 += __shfl_xor(a1, o); }
    if (lane == 0) {
        hW5[wave * 2 + 0] = a0;
        hW5[wave * 2 + 1] = a1;
        as_[wave] = a0 * asrc[0] + a1 * asrc[1];
        ad_[wave] = a0 * adst[0] + a1 * adst[1];
    }
}

// wave-per-node final aggregation (Co=2)
__global__ __launch_bounds__(256) void k_agg2(const float* __restrict__ hW5,
                                              const float* __restrict__ as_,
                                              const float* __restrict__ ad_,
                                              const int* __restrict__ rowptr,
                                              const int* __restrict__ col,
                                              const float* __restrict__ bias,
                                              float* __restrict__ out) {
    int wv = threadIdx.x >> 6, lane = threadIdx.x & 63;
    int node = blockIdx.x * 4 + wv;
    if (node >= N_NODES) return;
    int start = rowptr[node], end = rowptr[node + 1];
    int deg = end - start;
    float adi = ad_[node];
    float o0, o1;
    if (deg <= 64) {
        int cv = col[start + min(lane, deg - 1)];
        float logit = (lane < deg) ? leaky(as_[cv] + adi) : -1e30f;
        float m = logit;
#pragma unroll
        for (int o = 32; o; o >>= 1) m = fmaxf(m, __shfl_xor(m, o));
        float ex = __expf(logit - m);
        float den = ex;
#pragma unroll
        for (int o = 32; o; o >>= 1) den += __shfl_xor(den, o);
        float al = ex / den;
        float2 hv = make_float2(0.f, 0.f);
        if (lane < deg) hv = *(const float2*)&hW5[cv * 2];
        o0 = al * hv.x; o1 = al * hv.y;
#pragma unroll
        for (int o = 32; o; o >>= 1) { o0 += __shfl_xor(o0, o); o1 += __shfl_xor(o1, o); }
    } else {
        float m = -1e30f;
        for (int j = start + lane; j < end; j += 64)
            m = fmaxf(m, leaky(as_[col[j]] + adi));
        for (int o = 32; o; o >>= 1) m = fmaxf(m, __shfl_xor(m, o));
        float den = 0.f;
        for (int j = start + lane; j < end; j += 64)
            den += __expf(leaky(as_[col[j]] + adi) - m);
        for (int o = 32; o; o >>= 1) den += __shfl_xor(den, o);
        float inv = 1.f / den;
        o0 = 0.f; o1 = 0.f;
        for (int j = start + lane; j < end; j += 64) {
            int s = col[j];
            float al = __expf(leaky(as_[s] + adi) - m) * inv;
            o0 = fmaf(al, hW5[s * 2 + 0], o0);
            o1 = fmaf(al, hW5[s * 2 + 1], o1);
        }
        for (int o = 32; o; o >>= 1) { o0 += __shfl_xor(o0, o); o1 += __shfl_xor(o1, o); }
    }
    if (lane == 0) {
        out[node * 2 + 0] = o0 + bias[0];
        out[node * 2 + 1] = o1 + bias[1];
    }
}

extern "C" void kernel_launch(void* const* d_in, const int* in_sizes, int n_in,
                              void* d_out, int out_size, void* d_ws, size_t ws_size,
                              hipStream_t stream) {
    const float* x   = (const float*)d_in[0];
    const int*   ei  = (const int*)d_in[1];
    const float* W[5]  = {(const float*)d_in[2],  (const float*)d_in[6],
                          (const float*)d_in[10], (const float*)d_in[14],
                          (const float*)d_in[18]};
    const float* As[5] = {(const float*)d_in[3],  (const float*)d_in[7],
                          (const float*)d_in[11], (const float*)d_in[15],
                          (const float*)d_in[19]};
    const float* Ad[5] = {(const float*)d_in[4],  (const float*)d_in[8],
                          (const float*)d_in[12], (const float*)d_in[16],
                          (const float*)d_in[20]};
    const float* Bi[5] = {(const float*)d_in[5],  (const float*)d_in[9],
                          (const float*)d_in[13], (const float*)d_in[17],
                          (const float*)d_in[21]};
    float* out = (float*)d_out;

    // workspace layout (~108 MB); xa pair aliases bufX (disjoint lifetimes)
    char* w = (char*)d_ws;
    float* bufX = (float*)w;                 w += (size_t)N_NODES * C_HID * 4;   // hW fp32 (layers 2-4)
    unsigned short* xa_hi = (unsigned short*)bufX;                               // [MPAD,128] bf16 (layer 1)
    unsigned short* xa_lo = xa_hi + (size_t)MPAD * C_IN;
    unsigned short* pair_hi = (unsigned short*)w; w += (size_t)MPAD * C_HID * 2;
    unsigned short* pair_lo = (unsigned short*)w; w += (size_t)MPAD * C_HID * 2;
    unsigned short* Wth = (unsigned short*)w;     w += (size_t)C_HID * C_HID * 2;
    unsigned short* Wtl = (unsigned short*)w;     w += (size_t)C_HID * C_HID * 2;
    float* as_  = (float*)w;  w += N_NODES * 4;
    float* ad_  = (float*)w;  w += N_NODES * 4;   // contiguous after as_
    float* hW5  = (float*)w;  w += N_NODES * 2 * 4;
    float* ws_  = (float*)w;  w += C_IN * 4;
    float* wd_  = (float*)w;  w += C_IN * 4;
    float* alpha = (float*)w; w += (ET + 16) * 4;   // +16 pad (masked overrun reads)
    int* rowptr = (int*)w;    w += (N_NODES + 1) * 4 + 12;
    int* counts = (int*)w;    w += N_NODES * 4;
    int* col    = (int*)w;    w += (ET + 16) * 4;   // +16 pad, zeroed by k_fill

    const int TB = 256;
    // ---- CSR build ----
    k_zero<<<(N_NODES + TB - 1) / TB, TB, 0, stream>>>(counts, N_NODES);
    k_count<<<(ET + TB - 1) / TB, TB, 0, stream>>>(ei, counts);
    k_scan<<<1, 1024, 0, stream>>>(counts, rowptr);   // also writes cursor into counts
    k_fill<<<(ET + 16 + TB - 1) / TB, TB, 0, stream>>>(ei, counts, col);

    // pad rows of xa pair + pair
    k_padzero<<<((MPAD - N_NODES) * C_HID + TB - 1) / TB, TB, 0, stream>>>(xa_hi, xa_lo, pair_hi, pair_lo);

    const int gemmBlocks = NXB * NYB;   // 1570, swizzle-decoded in-kernel
    dim3 gathGrid(N_NODES / 8, 20);     // 2500 x 20: 2-node waves, 32-col slices
    int nodeWaveBlocks = (N_NODES + 3) / 4;

    // ---- layer 1 (reordered): logits from x, fused-softmax gather x, GEMM -> pair ----
    k_splitWT<<<dim3(C_IN / 64, C_HID / 64), TB, 0, stream>>>(W[0], Wth, Wtl, C_IN, (float*)0, 0);
    k_wa<<<32, TB, 0, stream>>>(W[0], As[0], Ad[0], ws_, wd_);   // 128 waves = 32 blocks
    k_logitx<<<nodeWaveBlocks, TB, 0, stream>>>(x, ws_, wd_, as_, ad_);
    k_gather_x<<<nodeWaveBlocks, TB, 0, stream>>>(x, as_, ad_, rowptr, col, xa_hi, xa_lo);
    k_mfma_gemm_pair<<<gemmBlocks, TB, 0, stream>>>(xa_hi, xa_lo, Wth, Wtl,
                                                    pair_hi, pair_lo, Bi[0], C_IN, N_NODES);

    // ---- layers 2..4: pair -> bufX (hW + logits) -> alpha -> pair ----
    for (int l = 1; l <= 3; ++l) {
        // splitWT also zeroes as_/ad_ (fused zerof)
        k_splitWT<<<dim3(C_HID / 64, C_HID / 64), TB, 0, stream>>>(W[l], Wth, Wtl, C_HID,
                                                                   as_, 2 * N_NODES);
        k_mfma_gemm<<<gemmBlocks, TB, 0, stream>>>(pair_hi, pair_lo, Wth, Wtl, bufX, C_HID, N_NODES,
                                                   As[l], Ad[l], as_, ad_);
        k_alpha<<<nodeWaveBlocks, TB, 0, stream>>>(as_, ad_, rowptr, col, alpha);
        k_gather32<<<gathGrid, TB, 0, stream>>>(bufX, alpha, rowptr, col, Bi[l], pair_hi, pair_lo);
    }

    // ---- layer 5: pair -> hW5 (N,2) + logits -> out ----
    k_gemm2<<<nodeWaveBlocks, TB, 0, stream>>>(pair_hi, pair_lo, W[4], As[4], Ad[4], hW5, as_, ad_);
    k_agg2<<<nodeWaveBlocks, TB, 0, stream>>>(hW5, as_, ad_, rowptr, col, Bi[4], out);
}

// Round 16
// 710.879 us; speedup vs baseline: 1.4212x; 1.4212x over previous
//
#include <hip/hip_runtime.h>
#include <math.h>

#define N_NODES 20000
#define MPAD 20096            // 157 * 128
#define E_EDGES 320000
#define ET (E_EDGES + N_NODES)   // edges incl. self-loops
#define C_HID 640
#define C_IN 128
#define NEG_SLOPE 0.2f

// GEMM tiling: BM=128, BN=64, BK=64; grid = NXB x 10 flattened with XCD swizzle
#define NXB 157               // MPAD/128
#define NYB 10                // C_HID/64
#define NXB_FULL 152          // (NXB/8)*8
#define IDS_MAIN 1520         // NXB_FULL * NYB

typedef __attribute__((ext_vector_type(8))) short bf16x8;   // 8 bf16 in 4 VGPRs
typedef __attribute__((ext_vector_type(4))) float f32x4;

__device__ __forceinline__ float leaky(float x) { return x > 0.f ? x : NEG_SLOPE * x; }

__device__ __forceinline__ unsigned short f2bf(float f) {
    unsigned u = __float_as_uint(f);
    unsigned r = (u + 0x7fffu + ((u >> 16) & 1u)) >> 16;
    return (unsigned short)r;
}
__device__ __forceinline__ float bf2f(unsigned short h) {
    return __uint_as_float(((unsigned)h) << 16);
}

__device__ __forceinline__ void gld16(const void* g, void* l) {
    __builtin_amdgcn_global_load_lds((const __attribute__((address_space(1))) unsigned int*)g,
                                     (__attribute__((address_space(3))) unsigned int*)l,
                                     16, 0, 0);
}

// XCD-aware swizzle: blocks sharing an A-stripe (same bx) get ids 8 apart -> same XCD (id%8)
__device__ __forceinline__ void decode_xy(int id, int& bx, int& by) {
    if (id < IDS_MAIN) {
        int g = id / 80;               // 80 = 8 bx * 10 by per group
        bx = g * 8 + (id & 7);
        by = (id % 80) >> 3;
    } else {
        int v = id - IDS_MAIN;         // 5 bx * 10 by tail
        bx = NXB_FULL + v % 5;
        by = v / 5;
    }
}

// ---------------- CSR build (by dst) ----------------
__global__ void k_zero(int* p, int n) {
    int i = blockIdx.x * blockDim.x + threadIdx.x;
    if (i < n) p[i] = 0;
}

__global__ void k_count(const int* __restrict__ ei, int* __restrict__ counts) {
    int j = blockIdx.x * blockDim.x + threadIdx.x;
    if (j >= ET) return;
    int d = (j < E_EDGES) ? ei[E_EDGES + j] : (j - E_EDGES);
    atomicAdd(&counts[d], 1);
}

// single-block scan; also overwrites counts[] with the exclusive prefix (cursor for k_fill)
__global__ __launch_bounds__(1024) void k_scan(int* __restrict__ counts,
                                               int* __restrict__ rowptr) {
    __shared__ int part[1024];
    int t = threadIdx.x;
    int base = t * 20;
    int incl[20];
    int s = 0;
#pragma unroll
    for (int k = 0; k < 20; k++) {
        int i = base + k;
        int v = (i < N_NODES) ? counts[i] : 0;
        s += v;
        incl[k] = s;
    }
    part[t] = s;
    __syncthreads();
    for (int off = 1; off < 1024; off <<= 1) {
        int x = (t >= off) ? part[t - off] : 0;
        __syncthreads();
        part[t] += x;
        __syncthreads();
    }
    int prefix = (t == 0) ? 0 : part[t - 1];
    if (t == 0) rowptr[0] = 0;
#pragma unroll
    for (int k = 0; k < 20; k++) {
        int i = base + k;
        if (i < N_NODES) {
            rowptr[i + 1] = prefix + incl[k];
            counts[i] = (k == 0) ? prefix : prefix + incl[k - 1];   // exclusive = row start
        }
    }
}

__global__ void k_fill(const int* __restrict__ ei, int* __restrict__ cursor, int* __restrict__ col) {
    int j = blockIdx.x * blockDim.x + threadIdx.x;
    if (j >= ET) return;
    int s, d;
    if (j < E_EDGES) { s = ei[j]; d = ei[E_EDGES + j]; }
    else { s = d = j - E_EDGES; }
    int pos = atomicAdd(&cursor[d], 1);
    col[pos] = s;
}

// ---------------- W transpose+split, LDS-tiled; also zeroes as_/ad_ (fused zerof) ----------------
__global__ __launch_bounds__(256) void k_splitWT(const float* __restrict__ W,
                                                 unsigned short* __restrict__ Wth,
                                                 unsigned short* __restrict__ Wtl, int K,
                                                 float* __restrict__ zbuf, int zn) {
    if (zbuf) {   // fused as_/ad_ zeroing
        int tid = ((blockIdx.y * gridDim.x + blockIdx.x) * 256 + threadIdx.x) * 2;
        if (tid < zn) zbuf[tid] = 0.f;
        if (tid + 1 < zn) zbuf[tid + 1] = 0.f;
    }
    __shared__ float tile[64][65];
    int t = threadIdx.x;
    int ki = blockIdx.x * 64, ni = blockIdx.y * 64;
    int tr = t >> 2;                 // 0..63
    int tc = (t & 3) * 16;           // 0,16,32,48
#pragma unroll
    for (int q = 0; q < 4; ++q) {
        float4 v = *(const float4*)&W[(size_t)(ki + tr) * C_HID + ni + tc + q * 4];
        tile[tr][tc + q * 4 + 0] = v.x;
        tile[tr][tc + q * 4 + 1] = v.y;
        tile[tr][tc + q * 4 + 2] = v.z;
        tile[tr][tc + q * 4 + 3] = v.w;
    }
    __syncthreads();
    unsigned short hh[16], ll[16];
#pragma unroll
    for (int j = 0; j < 16; ++j) {
        float w = tile[tc + j][tr];
        unsigned short h = f2bf(w);
        hh[j] = h;
        ll[j] = f2bf(w - bf2f(h));
    }
    size_t o = (size_t)(ni + tr) * K + ki + tc;
#pragma unroll
    for (int q = 0; q < 4; ++q) {
        *(ushort4*)&Wth[o + q * 4] = make_ushort4(hh[q*4], hh[q*4+1], hh[q*4+2], hh[q*4+3]);
        *(ushort4*)&Wtl[o + q * 4] = make_ushort4(ll[q*4], ll[q*4+1], ll[q*4+2], ll[q*4+3]);
    }
}

// zero pad rows of xa pair [MPAD,128] and pair [MPAD,640]
__global__ void k_padzero(unsigned short* __restrict__ xah, unsigned short* __restrict__ xal,
                          unsigned short* __restrict__ ph, unsigned short* __restrict__ pl) {
    int idx = blockIdx.x * blockDim.x + threadIdx.x;
    const int nx = (MPAD - N_NODES) * C_IN;
    const int np = (MPAD - N_NODES) * C_HID;
    if (idx < nx) {
        xah[N_NODES * C_IN + idx] = 0;
        xal[N_NODES * C_IN + idx] = 0;
    }
    if (idx < np) {
        ph[N_NODES * C_HID + idx] = 0;
        pl[N_NODES * C_HID + idx] = 0;
    }
}

// ws = W1 @ a_src (len 128), wd = W1 @ a_dst — 128 waves = 32 blocks
__global__ void k_wa(const float* __restrict__ W, const float* __restrict__ a_s,
                     const float* __restrict__ a_d,
                     float* __restrict__ ws_, float* __restrict__ wd_) {
    int wave = (blockIdx.x * blockDim.x + threadIdx.x) >> 6;
    int lane = threadIdx.x & 63;
    if (wave >= C_IN) return;
    const float* row = W + (size_t)wave * C_HID;
    float s = 0.f, d = 0.f;
#pragma unroll
    for (int c = lane; c < C_HID; c += 64) {
        float w = row[c];
        s = fmaf(w, a_s[c], s);
        d = fmaf(w, a_d[c], d);
    }
    for (int o = 32; o; o >>= 1) { s += __shfl_xor(s, o); d += __shfl_xor(d, o); }
    if (lane == 0) { ws_[wave] = s; wd_[wave] = d; }
}

// as_[n] = x[n,:].ws, ad_[n] = x[n,:].wd — wave per node
__global__ __launch_bounds__(256) void k_logitx(const float* __restrict__ x,
                                                const float* __restrict__ ws_,
                                                const float* __restrict__ wd_,
                                                float* __restrict__ as_, float* __restrict__ ad_) {
    int wave = (blockIdx.x * blockDim.x + threadIdx.x) >> 6;
    int lane = threadIdx.x & 63;
    if (wave >= N_NODES) return;
    float2 xv = ((const float2*)(x + (size_t)wave * C_IN))[lane];
    float2 wsv = ((const float2*)ws_)[lane];
    float2 wdv = ((const float2*)wd_)[lane];
    float s = xv.x * wsv.x + xv.y * wsv.y;
    float d = xv.x * wdv.x + xv.y * wdv.y;
    for (int o = 32; o; o >>= 1) { s += __shfl_xor(s, o); d += __shfl_xor(d, o); }
    if (lane == 0) { as_[wave] = s; ad_[wave] = d; }
}

// ---------------- per-edge softmax weights (layers 2-4): wave per dst node ----------------
__global__ __launch_bounds__(256) void k_alpha(const float* __restrict__ as_,
                                               const float* __restrict__ ad_,
                                               const int* __restrict__ rowptr,
                                               const int* __restrict__ col,
                                               float* __restrict__ alpha) {
    int wave = (blockIdx.x * blockDim.x + threadIdx.x) >> 6;
    int lane = threadIdx.x & 63;
    if (wave >= N_NODES) return;
    int start = rowptr[wave], end = rowptr[wave + 1];
    float adi = ad_[wave];
    float m = -1e30f;
    for (int j = start + lane; j < end; j += 64)
        m = fmaxf(m, leaky(as_[col[j]] + adi));
    for (int o = 32; o; o >>= 1) m = fmaxf(m, __shfl_xor(m, o));
    float den = 0.f;
    for (int j = start + lane; j < end; j += 64)
        den += __expf(leaky(as_[col[j]] + adi) - m);
    for (int o = 32; o; o >>= 1) den += __shfl_xor(den, o);
    float inv = 1.f / den;
    for (int j = start + lane; j < end; j += 64)
        alpha[j] = __expf(leaky(as_[col[j]] + adi) - m) * inv;
}

// ---------------- split-bf16 MFMA GEMM (BM=128,BN=64,BK=64) + fused logits (layers 2-4) ----------------
// 10 K-iterations -> half the barrier drains vs BK=32, 2x MFMA per drain.
// LDS 48KB: Ahi[0,8K) Alo[8K,16K) Bhi[16K,20K) Blo[20K,24K) (ushort idx).
// Bank swizzle: chunk c of row r stored at c^(r&7); readers XOR to match (2-way, free).
__global__ __launch_bounds__(256) void k_mfma_gemm(
    const unsigned short* __restrict__ Ahi, const unsigned short* __restrict__ Alo,
    const unsigned short* __restrict__ Bth, const unsigned short* __restrict__ Btl,
    float* __restrict__ C, int K, int M,
    const float* __restrict__ asrc, const float* __restrict__ adst,
    float* __restrict__ as_, float* __restrict__ ad_) {
    __shared__ unsigned short lds[24576];
    const int t = threadIdx.x;
    const int lane = t & 63, wv = t >> 6;
    const int wm = wv >> 1, wn = wv & 1;
    const int quad = lane >> 4, cl = lane & 15;
    int bx, by;
    decode_xy(blockIdx.x, bx, by);
    const int rowBase = bx * 128;
    const int colBase = by * 64;
    const int sr = t >> 3;                 // staging row within 32-row pass
    const int scg = ((t & 7) ^ (sr & 7)) * 8;   // swizzled global chunk (ushort off)

    f32x4 acc[4][2];
#pragma unroll
    for (int i = 0; i < 4; i++)
#pragma unroll
        for (int j = 0; j < 2; j++)
            acc[i][j] = (f32x4){0.f, 0.f, 0.f, 0.f};

    for (int k0 = 0; k0 < K; k0 += 64) {
        __syncthreads();
#pragma unroll
        for (int p = 0; p < 4; ++p) {       // A pair: 128 rows
            int r = p * 32 + sr;
            size_t ga = (size_t)(rowBase + r) * K + k0 + scg;
            int lo = p * 2048 + t * 8;
            gld16(Ahi + ga, &lds[lo]);
            gld16(Alo + ga, &lds[8192 + lo]);
        }
#pragma unroll
        for (int p = 0; p < 2; ++p) {       // B pair: 64 rows
            int r = p * 32 + sr;
            size_t gb = (size_t)(colBase + r) * K + k0 + scg;
            int lo = p * 2048 + t * 8;
            gld16(Bth + gb, &lds[16384 + lo]);
            gld16(Btl + gb, &lds[20480 + lo]);
        }
        __syncthreads();

#pragma unroll
        for (int ks = 0; ks < 2; ++ks) {
            bf16x8 ah[4], al[4], bh[2], bl[2];
#pragma unroll
            for (int i = 0; i < 4; ++i) {
                int row = wm * 64 + i * 16 + cl;
                int am = row * 64 + (((ks * 4 + quad) ^ (row & 7)) * 8);
                ah[i] = *(const bf16x8*)&lds[am];
                al[i] = *(const bf16x8*)&lds[8192 + am];
            }
#pragma unroll
            for (int j = 0; j < 2; ++j) {
                int row = wn * 32 + j * 16 + cl;
                int bn = row * 64 + (((ks * 4 + quad) ^ (row & 7)) * 8);
                bh[j] = *(const bf16x8*)&lds[16384 + bn];
                bl[j] = *(const bf16x8*)&lds[20480 + bn];
            }
#pragma unroll
            for (int i = 0; i < 4; ++i)
#pragma unroll
                for (int j = 0; j < 2; ++j) {
                    acc[i][j] = __builtin_amdgcn_mfma_f32_16x16x32_bf16(ah[i], bh[j], acc[i][j], 0, 0, 0);
                    acc[i][j] = __builtin_amdgcn_mfma_f32_16x16x32_bf16(ah[i], bl[j], acc[i][j], 0, 0, 0);
                    acc[i][j] = __builtin_amdgcn_mfma_f32_16x16x32_bf16(al[i], bh[j], acc[i][j], 0, 0, 0);
                }
        }
    }

    // C stores; C/D layout: col = lane&15, row = quad*4 + reg
#pragma unroll
    for (int i = 0; i < 4; ++i)
#pragma unroll
        for (int j = 0; j < 2; ++j) {
            int colC = colBase + wn * 32 + j * 16 + cl;
#pragma unroll
            for (int rr = 0; rr < 4; ++rr) {
                int rowC = rowBase + wm * 64 + i * 16 + quad * 4 + rr;
                if (rowC < M) C[(size_t)rowC * C_HID + colC] = acc[i][j][rr];
            }
        }

    // fused logits epilogue
    float av[2], dv[2];
#pragma unroll
    for (int j = 0; j < 2; ++j) {
        int cn = colBase + wn * 32 + j * 16 + cl;
        av[j] = asrc[cn];
        dv[j] = adst[cn];
    }
#pragma unroll
    for (int i = 0; i < 4; ++i)
#pragma unroll
        for (int rr = 0; rr < 4; ++rr) {
            float s = 0.f, d = 0.f;
#pragma unroll
            for (int j = 0; j < 2; ++j) {
                float v = acc[i][j][rr];
                s = fmaf(v, av[j], s);
                d = fmaf(v, dv[j], d);
            }
#pragma unroll
            for (int o = 8; o >= 1; o >>= 1) {
                s += __shfl_xor(s, o);
                d += __shfl_xor(d, o);
            }
            int rowC = rowBase + wm * 64 + i * 16 + quad * 4 + rr;
            if (cl == 0 && rowC < M) {
                atomicAdd(&as_[rowC], s);
                atomicAdd(&ad_[rowC], d);
            }
        }
}

// ---------------- layer-1 GEMM (BK=64): pair output epilogue (bias+relu+split) ----------------
__global__ __launch_bounds__(256) void k_mfma_gemm_pair(
    const unsigned short* __restrict__ Ahi, const unsigned short* __restrict__ Alo,
    const unsigned short* __restrict__ Bth, const unsigned short* __restrict__ Btl,
    unsigned short* __restrict__ Oh, unsigned short* __restrict__ Ol,
    const float* __restrict__ bias, int K, int M) {
    __shared__ unsigned short lds[24576];
    const int t = threadIdx.x;
    const int lane = t & 63, wv = t >> 6;
    const int wm = wv >> 1, wn = wv & 1;
    const int quad = lane >> 4, cl = lane & 15;
    int bx, by;
    decode_xy(blockIdx.x, bx, by);
    const int rowBase = bx * 128;
    const int colBase = by * 64;
    const int sr = t >> 3;
    const int scg = ((t & 7) ^ (sr & 7)) * 8;

    f32x4 acc[4][2];
#pragma unroll
    for (int i = 0; i < 4; i++)
#pragma unroll
        for (int j = 0; j < 2; j++)
            acc[i][j] = (f32x4){0.f, 0.f, 0.f, 0.f};

    for (int k0 = 0; k0 < K; k0 += 64) {
        __syncthreads();
#pragma unroll
        for (int p = 0; p < 4; ++p) {
            int r = p * 32 + sr;
            size_t ga = (size_t)(rowBase + r) * K + k0 + scg;
            int lo = p * 2048 + t * 8;
            gld16(Ahi + ga, &lds[lo]);
            gld16(Alo + ga, &lds[8192 + lo]);
        }
#pragma unroll
        for (int p = 0; p < 2; ++p) {
            int r = p * 32 + sr;
            size_t gb = (size_t)(colBase + r) * K + k0 + scg;
            int lo = p * 2048 + t * 8;
            gld16(Bth + gb, &lds[16384 + lo]);
            gld16(Btl + gb, &lds[20480 + lo]);
        }
        __syncthreads();

#pragma unroll
        for (int ks = 0; ks < 2; ++ks) {
            bf16x8 ah[4], al[4], bh[2], bl[2];
#pragma unroll
            for (int i = 0; i < 4; ++i) {
                int row = wm * 64 + i * 16 + cl;
                int am = row * 64 + (((ks * 4 + quad) ^ (row & 7)) * 8);
                ah[i] = *(const bf16x8*)&lds[am];
                al[i] = *(const bf16x8*)&lds[8192 + am];
            }
#pragma unroll
            for (int j = 0; j < 2; ++j) {
                int row = wn * 32 + j * 16 + cl;
                int bn = row * 64 + (((ks * 4 + quad) ^ (row & 7)) * 8);
                bh[j] = *(const bf16x8*)&lds[16384 + bn];
                bl[j] = *(const bf16x8*)&lds[20480 + bn];
            }
#pragma unroll
            for (int i = 0; i < 4; ++i)
#pragma unroll
                for (int j = 0; j < 2; ++j) {
                    acc[i][j] = __builtin_amdgcn_mfma_f32_16x16x32_bf16(ah[i], bh[j], acc[i][j], 0, 0, 0);
                    acc[i][j] = __builtin_amdgcn_mfma_f32_16x16x32_bf16(ah[i], bl[j], acc[i][j], 0, 0, 0);
                    acc[i][j] = __builtin_amdgcn_mfma_f32_16x16x32_bf16(al[i], bh[j], acc[i][j], 0, 0, 0);
                }
        }
    }

#pragma unroll
    for (int j = 0; j < 2; ++j) {
        int colC = colBase + wn * 32 + j * 16 + cl;
        float bv = bias[colC];
#pragma unroll
        for (int i = 0; i < 4; ++i)
#pragma unroll
            for (int rr = 0; rr < 4; ++rr) {
                int rowC = rowBase + wm * 64 + i * 16 + quad * 4 + rr;
                if (rowC < M) {
                    float v = fmaxf(acc[i][j][rr] + bv, 0.f);   // ReLU (layer 1)
                    unsigned short h = f2bf(v);
                    Oh[(size_t)rowC * C_HID + colC] = h;
                    Ol[(size_t)rowC * C_HID + colC] = f2bf(v - bf2f(h));
                }
            }
    }
}

// ---------------- weighted gather (layers 2-4): wave = (node, 64-col chunk) ----------------
// Scalar-pipe col/alpha loads, contiguous 16-edge batches; backward-aligned masked tail.
__global__ __launch_bounds__(256) void k_gather64(const float* __restrict__ hW,
                                                  const float* __restrict__ alpha,
                                                  const int* __restrict__ rowptr,
                                                  const int* __restrict__ col,
                                                  const float* __restrict__ bias,
                                                  unsigned short* __restrict__ outh,
                                                  unsigned short* __restrict__ outl) {
    int lane = threadIdx.x & 63;
    int node = __builtin_amdgcn_readfirstlane(blockIdx.x * 4 + (threadIdx.x >> 6));
    int c = blockIdx.y;
    if (node >= N_NODES) return;
    int start = rowptr[node], end = rowptr[node + 1];
    const float* base = hW + c * 64 + lane;
    float ax = 0.f;

    int j0 = start;
    for (; j0 + 16 <= end; j0 += 16) {
        int cv[16];
        float av[16];
#pragma unroll
        for (int q = 0; q < 16; ++q) { cv[q] = col[j0 + q]; av[q] = alpha[j0 + q]; }
        float r[16];
#pragma unroll
        for (int q = 0; q < 16; ++q) r[q] = base[(size_t)cv[q] * C_HID];
#pragma unroll
        for (int q = 0; q < 16; ++q) ax = fmaf(av[q], r[q], ax);
    }
    if (j0 < end) {
        int jb = end - 16; if (jb < 0) jb = 0;
        int cv[16];
        float av[16];
#pragma unroll
        for (int q = 0; q < 16; ++q) {
            cv[q] = col[jb + q];
            av[q] = (jb + q >= j0) ? alpha[jb + q] : 0.f;
        }
        float r[16];
#pragma unroll
        for (int q = 0; q < 16; ++q) r[q] = base[(size_t)cv[q] * C_HID];
#pragma unroll
        for (int q = 0; q < 16; ++q) ax = fmaf(av[q], r[q], ax);
    }

    float v0 = fmaxf(ax + bias[c * 64 + lane], 0.f);   // layers 2-4 ReLU
    unsigned short h0 = f2bf(v0);
    size_t o = (size_t)node * C_HID + c * 64 + lane;
    outh[o] = h0;
    outl[o] = f2bf(v0 - bf2f(h0));
}

// ---------------- layer-1 gather: fused softmax + gather raw x (128 cols, single pass) ----------------
__global__ __launch_bounds__(256) void k_gather_x(const float* __restrict__ x,
                                                  const float* __restrict__ as_,
                                                  const float* __restrict__ ad_,
                                                  const int* __restrict__ rowptr,
                                                  const int* __restrict__ col,
                                                  unsigned short* __restrict__ outh,
                                                  unsigned short* __restrict__ outl) {
    int wv = threadIdx.x >> 6, lane = threadIdx.x & 63;
    int node = blockIdx.x * 4 + wv;
    if (node >= N_NODES) return;
    int start = rowptr[node], end = rowptr[node + 1];
    int deg = end - start;
    const float* base = x + lane * 2;
    float ax = 0.f, ay = 0.f;
    float adi = ad_[node];

    if (deg <= 64) {
        int col_v = col[start + min(lane, deg - 1)];
        float asv = as_[col_v];
        float logit = (lane < deg) ? leaky(asv + adi) : -1e30f;
        float m = logit;
#pragma unroll
        for (int o = 32; o; o >>= 1) m = fmaxf(m, __shfl_xor(m, o));
        float ex = __expf(logit - m);
        float den = ex;
#pragma unroll
        for (int o = 32; o; o >>= 1) den += __shfl_xor(den, o);
        float alpha_v = ex / den;

        for (int e0 = 0; e0 < deg; e0 += 8) {
            float2 r[8];
            float a[8];
#pragma unroll
            for (int q = 0; q < 8; ++q) {
                int e = e0 + q;
                int ec = min(e, deg - 1);
                int s = __shfl(col_v, ec);
                float ar = __shfl(alpha_v, ec);
                a[q] = (e < deg) ? ar : 0.f;
                r[q] = *(const float2*)(base + (size_t)s * C_IN);
            }
#pragma unroll
            for (int q = 0; q < 8; ++q) {
                ax = fmaf(a[q], r[q].x, ax);
                ay = fmaf(a[q], r[q].y, ay);
            }
        }
    } else {
        float m = -1e30f;
        for (int j = start + lane; j < end; j += 64)
            m = fmaxf(m, leaky(as_[col[j]] + adi));
        for (int o = 32; o; o >>= 1) m = fmaxf(m, __shfl_xor(m, o));
        float den = 0.f;
        for (int j = start + lane; j < end; j += 64)
            den += __expf(leaky(as_[col[j]] + adi) - m);
        for (int o = 32; o; o >>= 1) den += __shfl_xor(den, o);
        float inv = 1.f / den;
        for (int j = start; j < end; ++j) {
            int s = col[j];
            float a = __expf(leaky(as_[s] + adi) - m) * inv;
            float2 r = *(const float2*)(base + (size_t)s * C_IN);
            ax = fmaf(a, r.x, ax);
            ay = fmaf(a, r.y, ay);
        }
    }

    unsigned short h0 = f2bf(ax), h1 = f2bf(ay);
    size_t o = (size_t)node * C_IN + lane * 2;
    *(ushort2*)&outh[o] = make_ushort2(h0, h1);
    *(ushort2*)&outl[o] = make_ushort2(f2bf(ax - bf2f(h0)), f2bf(ay - bf2f(h1)));
}

// ---------------- layer 5 (Co=2): hW5 + fused logits ----------------
__global__ __launch_bounds__(256) void k_gemm2(const unsigned short* __restrict__ hh,
                                               const unsigned short* __restrict__ hl,
                                               const float* __restrict__ W,
                                               const float* __restrict__ asrc,
                                               const float* __restrict__ adst,
                                               float* __restrict__ hW5,
                                               float* __restrict__ as_,
                                               float* __restrict__ ad_) {
    int wave = (blockIdx.x * blockDim.x + threadIdx.x) >> 6;
    int lane = threadIdx.x & 63;
    if (wave >= N_NODES) return;
    const ushort2* rh = (const ushort2*)(hh + (size_t)wave * C_HID);
    const ushort2* rl = (const ushort2*)(hl + (size_t)wave * C_HID);
    float a0 = 0.f, a1 = 0.f;
#pragma unroll
    for (int k2 = lane; k2 < C_HID / 2; k2 += 64) {
        ushort2 h2 = rh[k2];
        ushort2 l2 = rl[k2];
        float v0 = bf2f(h2.x) + bf2f(l2.x);
        float v1 = bf2f(h2.y) + bf2f(l2.y);
        int k = k2 * 2;
        a0 = fmaf(v0, W[k * 2 + 0], a0);
        a1 = fmaf(v0, W[k * 2 + 1], a1);
        a0 = fmaf(v1, W[k * 2 + 2], a0);
        a1 = fmaf(v1, W[k * 2 + 3], a1);
    }
    for (int o = 32; o; o >>= 1) { a0 += __shfl_xor(a0, o); a1 += __shfl_xor(a1, o); }
    if (lane == 0) {
        hW5[wave * 2 + 0] = a0;
        hW5[wave * 2 + 1] = a1;
        as_[wave] = a0 * asrc[0] + a1 * asrc[1];
        ad_[wave] = a0 * adst[0] + a1 * adst[1];
    }
}

// wave-per-node final aggregation (Co=2)
__global__ __launch_bounds__(256) void k_agg2(const float* __restrict__ hW5,
                                              const float* __restrict__ as_,
                                              const float* __restrict__ ad_,
                                              const int* __restrict__ rowptr,
                                              const int* __restrict__ col,
                                              const float* __restrict__ bias,
                                              float* __restrict__ out) {
    int wv = threadIdx.x >> 6, lane = threadIdx.x & 63;
    int node = blockIdx.x * 4 + wv;
    if (node >= N_NODES) return;
    int start = rowptr[node], end = rowptr[node + 1];
    int deg = end - start;
    float adi = ad_[node];
    float o0, o1;
    if (deg <= 64) {
        int cv = col[start + min(lane, deg - 1)];
        float logit = (lane < deg) ? leaky(as_[cv] + adi) : -1e30f;
        float m = logit;
#pragma unroll
        for (int o = 32; o; o >>= 1) m = fmaxf(m, __shfl_xor(m, o));
        float ex = __expf(logit - m);
        float den = ex;
#pragma unroll
        for (int o = 32; o; o >>= 1) den += __shfl_xor(den, o);
        float al = ex / den;
        float2 hv = make_float2(0.f, 0.f);
        if (lane < deg) hv = *(const float2*)&hW5[cv * 2];
        o0 = al * hv.x; o1 = al * hv.y;
#pragma unroll
        for (int o = 32; o; o >>= 1) { o0 += __shfl_xor(o0, o); o1 += __shfl_xor(o1, o); }
    } else {
        float m = -1e30f;
        for (int j = start + lane; j < end; j += 64)
            m = fmaxf(m, leaky(as_[col[j]] + adi));
        for (int o = 32; o; o >>= 1) m = fmaxf(m, __shfl_xor(m, o));
        float den = 0.f;
        for (int j = start + lane; j < end; j += 64)
            den += __expf(leaky(as_[col[j]] + adi) - m);
        for (int o = 32; o; o >>= 1) den += __shfl_xor(den, o);
        float inv = 1.f / den;
        o0 = 0.f; o1 = 0.f;
        for (int j = start + lane; j < end; j += 64) {
            int s = col[j];
            float al = __expf(leaky(as_[s] + adi) - m) * inv;
            o0 = fmaf(al, hW5[s * 2 + 0], o0);
            o1 = fmaf(al, hW5[s * 2 + 1], o1);
        }
        for (int o = 32; o; o >>= 1) { o0 += __shfl_xor(o0, o); o1 += __shfl_xor(o1, o); }
    }
    if (lane == 0) {
        out[node * 2 + 0] = o0 + bias[0];
        out[node * 2 + 1] = o1 + bias[1];
    }
}

extern "C" void kernel_launch(void* const* d_in, const int* in_sizes, int n_in,
                              void* d_out, int out_size, void* d_ws, size_t ws_size,
                              hipStream_t stream) {
    const float* x   = (const float*)d_in[0];
    const int*   ei  = (const int*)d_in[1];
    const float* W[5]  = {(const float*)d_in[2],  (const float*)d_in[6],
                          (const float*)d_in[10], (const float*)d_in[14],
                          (const float*)d_in[18]};
    const float* As[5] = {(const float*)d_in[3],  (const float*)d_in[7],
                          (const float*)d_in[11], (const float*)d_in[15],
                          (const float*)d_in[19]};
    const float* Ad[5] = {(const float*)d_in[4],  (const float*)d_in[8],
                          (const float*)d_in[12], (const float*)d_in[16],
                          (const float*)d_in[20]};
    const float* Bi[5] = {(const float*)d_in[5],  (const float*)d_in[9],
                          (const float*)d_in[13], (const float*)d_in[17],
                          (const float*)d_in[21]};
    float* out = (float*)d_out;

    // workspace layout (~108 MB); xa pair aliases bufX (disjoint lifetimes)
    char* w = (char*)d_ws;
    float* bufX = (float*)w;                 w += (size_t)N_NODES * C_HID * 4;   // hW fp32 (layers 2-4)
    unsigned short* xa_hi = (unsigned short*)bufX;                               // [MPAD,128] bf16 (layer 1)
    unsigned short* xa_lo = xa_hi + (size_t)MPAD * C_IN;
    unsigned short* pair_hi = (unsigned short*)w; w += (size_t)MPAD * C_HID * 2;
    unsigned short* pair_lo = (unsigned short*)w; w += (size_t)MPAD * C_HID * 2;
    unsigned short* Wth = (unsigned short*)w;     w += (size_t)C_HID * C_HID * 2;
    unsigned short* Wtl = (unsigned short*)w;     w += (size_t)C_HID * C_HID * 2;
    float* as_  = (float*)w;  w += N_NODES * 4;
    float* ad_  = (float*)w;  w += N_NODES * 4;   // contiguous after as_
    float* hW5  = (float*)w;  w += N_NODES * 2 * 4;
    float* ws_  = (float*)w;  w += C_IN * 4;
    float* wd_  = (float*)w;  w += C_IN * 4;
    float* alpha = (float*)w; w += ET * 4;
    int* rowptr = (int*)w;    w += (N_NODES + 1) * 4 + 12;
    int* counts = (int*)w;    w += N_NODES * 4;
    int* col    = (int*)w;    w += ET * 4;

    const int TB = 256;
    // ---- CSR build ----
    k_zero<<<(N_NODES + TB - 1) / TB, TB, 0, stream>>>(counts, N_NODES);
    k_count<<<(ET + TB - 1) / TB, TB, 0, stream>>>(ei, counts);
    k_scan<<<1, 1024, 0, stream>>>(counts, rowptr);   // also writes cursor into counts
    k_fill<<<(ET + TB - 1) / TB, TB, 0, stream>>>(ei, counts, col);

    // pad rows of xa pair + pair
    k_padzero<<<((MPAD - N_NODES) * C_HID + TB - 1) / TB, TB, 0, stream>>>(xa_hi, xa_lo, pair_hi, pair_lo);

    const int gemmBlocks = NXB * NYB;   // 1570, swizzle-decoded in-kernel
    dim3 gathGrid(N_NODES / 4, 10);     // 5000 x 10, 64-col slices
    int nodeWaveBlocks = (N_NODES + 3) / 4;

    // ---- layer 1 (reordered): logits from x, fused-softmax gather x, GEMM -> pair ----
    k_splitWT<<<dim3(C_IN / 64, C_HID / 64), TB, 0, stream>>>(W[0], Wth, Wtl, C_IN, (float*)0, 0);
    k_wa<<<32, TB, 0, stream>>>(W[0], As[0], Ad[0], ws_, wd_);   // 128 waves = 32 blocks
    k_logitx<<<nodeWaveBlocks, TB, 0, stream>>>(x, ws_, wd_, as_, ad_);
    k_gather_x<<<nodeWaveBlocks, TB, 0, stream>>>(x, as_, ad_, rowptr, col, xa_hi, xa_lo);
    k_mfma_gemm_pair<<<gemmBlocks, TB, 0, stream>>>(xa_hi, xa_lo, Wth, Wtl,
                                                    pair_hi, pair_lo, Bi[0], C_IN, N_NODES);

    // ---- layers 2..4: pair -> bufX (hW + logits) -> alpha -> pair ----
    for (int l = 1; l <= 3; ++l) {
        // splitWT also zeroes as_/ad_ (fused zerof)
        k_splitWT<<<dim3(C_HID / 64, C_HID / 64), TB, 0, stream>>>(W[l], Wth, Wtl, C_HID,
                                                                   as_, 2 * N_NODES);
        k_mfma_gemm<<<gemmBlocks, TB, 0, stream>>>(pair_hi, pair_lo, Wth, Wtl, bufX, C_HID, N_NODES,
                                                   As[l], Ad[l], as_, ad_);
        k_alpha<<<nodeWaveBlocks, TB, 0, stream>>>(as_, ad_, rowptr, col, alpha);
        k_gather64<<<gathGrid, TB, 0, stream>>>(bufX, alpha, rowptr, col, Bi[l], pair_hi, pair_lo);
    }

    // ---- layer 5: pair -> hW5 (N,2) + logits -> out ----
    k_gemm2<<<nodeWaveBlocks, TB, 0, stream>>>(pair_hi, pair_lo, W[4], As[4], Ad[4], hW5, as_, ad_);
    k_agg2<<<nodeWaveBlocks, TB, 0, stream>>>(hW5, as_, ad_, rowptr, col, Bi[4], out);
}